// Round 12
// baseline (160.139 us; speedup 1.0000x reference)
//
#include <hip/hip_runtime.h>
#include <hip/hip_fp16.h>
#include <math.h>

// Problem constants: N=500, DEG=16, E=8000, B=8, T=12 (BT=96), H=64, F=32
#define N_NODES 500
#define DEG     16
#define E_EDGES 8000
#define BT      96
#define H_      64
#define F_      32

typedef _Float16 f16;
typedef f16   half8v  __attribute__((ext_vector_type(8)));
typedef f16   half4v  __attribute__((ext_vector_type(4)));
typedef f16   half2v  __attribute__((ext_vector_type(2)));
typedef float f32x4v  __attribute__((ext_vector_type(4)));

#if __has_builtin(__builtin_amdgcn_exp2f)
#define EXP2F(x) __builtin_amdgcn_exp2f(x)
#else
#define EXP2F(x) exp2f(x)
#endif

#define LOG2E 1.44269504088896f

__device__ __forceinline__ float sigmoidf_(float x) {
    return 1.0f / (1.0f + __expf(-x));
}

__device__ __forceinline__ float dot2f_(half2v a, half2v b, float c) {
#if __has_builtin(__builtin_amdgcn_fdot2)
    return __builtin_amdgcn_fdot2(a, b, c, false);
#else
    return fmaf((float)a.x, (float)b.x, fmaf((float)a.y, (float)b.y, c));
#endif
}

// ---------------------------------------------------------------------------
// Kernel P (fused prep): blocks 0..31 = hyper MLP -> edge_pack
// {src*80 (LDS byte offset), h0h1 fp16x2}; blocks 32..127 = weight transpose
// -> wTh[c][jj][h] fp16, PRE-SCALED by log2(e) (leaky commutes with positive
// scale; fused kernel uses exp2 directly).
// plane c: 0=A_U 1=B_U 2=C_U 3=A_V 4=B_V 5=C_V; A=W3[0].view(128,64),
// B=W3[1], C=b3; U rows 0..63, V rows 64..127.
// ---------------------------------------------------------------------------
__global__ __launch_bounds__(256) void prep_kernel(
        const float* __restrict__ feature, const float* __restrict__ dist,
        const float* __restrict__ W1, const float* __restrict__ b1,
        const float* __restrict__ W2, const float* __restrict__ b2,
        const int* __restrict__ src,
        const float* __restrict__ W3, const float* __restrict__ b3,
        uint2* __restrict__ edge_pack, f16* __restrict__ wTh) {
    if (blockIdx.x >= 32) {
        int i = (blockIdx.x - 32) * 256 + threadIdx.x;
        if (i >= 6 * 64 * 64) return;
        int c  = i >> 12;
        int jj = (i >> 6) & 63;
        int h  = i & 63;
        const float* plane = (c % 3 == 0) ? W3 : (c % 3 == 1) ? (W3 + 8192) : b3;
        int rowbase = (c < 3) ? 0 : 64;
        wTh[i] = (f16)(plane[(rowbase + h) * 64 + jj] * LOG2E);
        return;
    }

    __shared__ float sW1[65 * 16];
    __shared__ float sb1[16];
    __shared__ float sW2[32];
    __shared__ float sb2[2];
    for (int i = threadIdx.x; i < 65 * 16; i += blockDim.x) sW1[i] = W1[i];
    if (threadIdx.x < 16) sb1[threadIdx.x] = b1[threadIdx.x];
    if (threadIdx.x < 32) sW2[threadIdx.x] = W2[threadIdx.x];
    if (threadIdx.x < 2)  sb2[threadIdx.x] = b2[threadIdx.x];
    __syncthreads();

    int e = blockIdx.x * 256 + threadIdx.x;
    if (e >= E_EDGES) return;
    int s = src[e];
    int d = e >> 4;                 // dst = repeat(arange(500),16)
    float fs[F_], fd[F_];
    const float4* f4 = (const float4*)feature;
    #pragma unroll
    for (int k = 0; k < 8; k++) {
        float4 v = f4[s * 8 + k];
        fs[4*k] = v.x; fs[4*k+1] = v.y; fs[4*k+2] = v.z; fs[4*k+3] = v.w;
    }
    #pragma unroll
    for (int k = 0; k < 8; k++) {
        float4 v = f4[d * 8 + k];
        fd[4*k] = v.x; fd[4*k+1] = v.y; fd[4*k+2] = v.z; fd[4*k+3] = v.w;
    }
    float dv = dist[e];

    float h1v[16];
    #pragma unroll
    for (int m = 0; m < 16; m++) {
        float acc = sb1[m] + dv * sW1[64 * 16 + m];
        #pragma unroll
        for (int f = 0; f < F_; f++) acc += fs[f] * sW1[f * 16 + m];
        #pragma unroll
        for (int f = 0; f < F_; f++) acc += fd[f] * sW1[(F_ + f) * 16 + m];
        h1v[m] = sigmoidf_(acc);
    }
    float o0 = sb2[0], o1 = sb2[1];
    #pragma unroll
    for (int m = 0; m < 16; m++) {
        o0 += h1v[m] * sW2[m * 2 + 0];
        o1 += h1v[m] * sW2[m * 2 + 1];
    }
    __half2 hh = __floats2half2_rn(sigmoidf_(o0), sigmoidf_(o1));
    uint2 ep;
    ep.x = (unsigned)(s * 80);      // pre-multiplied sU row byte-offset
    ep.y = *(unsigned*)&hh;
    edge_pack[e] = ep;
}

// ---------------------------------------------------------------------------
// Kernel F (fused GEMM + segment softmax). Grid = 8 jh x 96 bt, jh-major.
// 512 thr (8 waves). LDS = sU ONLY (40 KB) -> 4 blocks/CU = 32 waves/CU
// (R11: sV in LDS -> 80 KB -> 2 blocks/CU, Occupancy 30%, latency-bound;
// V has ZERO reuse so it moves to a per-block GLOBAL scratch: phase 1
// writes it coalesced, __syncthreads (drains vmcnt before s_barrier ->
// same-block global writes visible), phase 2 reads it back as one fully
// coalesced b128/lane, L2-hot). SQ_LDS_BANK_CONFLICT was identical
// (2,363,136) across R9/R10/R11 -> it's inherent to the random-row gather,
// not the epilogue; left as-is.
// ---------------------------------------------------------------------------
__global__ __launch_bounds__(512, 8) void fused_kernel(
        const float* __restrict__ state,
        const f16* __restrict__ wTh,
        const uint2* __restrict__ edge_pack,
        const float* __restrict__ gate,
        char* __restrict__ Vscratch,          // 32 KB per block
        float2* __restrict__ out2) {
    __shared__ float4 sU[N_NODES * 5];   // 40 KB, 80 B per node row

    int bt  = blockIdx.x % BT;
    int jh  = blockIdx.x / BT;
    int tid = threadIdx.x;
    int wv   = tid >> 6;
    int lane = tid & 63;
    int col  = lane & 15;
    int quad = lane >> 4;

    char* vgBase = Vscratch + (size_t)blockIdx.x * 32768;

    // B fragments: tile t covers plane t + 3*(col>>3), jj = jh*8 + (col&7)
    int jjglob = jh * 8 + (col & 7);
    int pside  = col >> 3;              // 0 = U planes, 1 = V planes
    half8v bfr[3][2];
    #pragma unroll
    for (int t = 0; t < 3; t++) {
        int plane = t + 3 * pside;
        const f16* wp = wTh + (plane * 64 + jjglob) * 64;
        bfr[t][0] = *(const half8v*)&wp[quad * 8];
        bfr[t][1] = *(const half8v*)&wp[32 + quad * 8];
    }

    const size_t sbase = (size_t)bt * N_NODES * H_;
    char* dstBase = pside ? vgBase : (char*)sU;
    int   rstride = pside ? 4 : 5;      // float4 row stride

    // ---- Phase 1: GEMM; U -> LDS pack, V -> global scratch
    for (int pass = 0; pass < 4; pass++) {
        int row0 = pass * 128 + wv * 16;
        int arow = row0 + col;
        int arowc = arow < N_NODES ? arow : N_NODES - 1;   // clamp tail reads
        const float* srow = state + sbase + (size_t)arowc * H_;
        float4 p0 = *(const float4*)&srow[quad * 8];
        float4 p1 = *(const float4*)&srow[quad * 8 + 4];
        float4 p2 = *(const float4*)&srow[32 + quad * 8];
        float4 p3 = *(const float4*)&srow[32 + quad * 8 + 4];
        half8v a0 = { (f16)p0.x,(f16)p0.y,(f16)p0.z,(f16)p0.w,
                      (f16)p1.x,(f16)p1.y,(f16)p1.z,(f16)p1.w };
        half8v a1 = { (f16)p2.x,(f16)p2.y,(f16)p2.z,(f16)p2.w,
                      (f16)p3.x,(f16)p3.y,(f16)p3.z,(f16)p3.w };

        f32x4v acc[3];
        #pragma unroll
        for (int t = 0; t < 3; t++) {
            f32x4v a = {0.0f, 0.0f, 0.0f, 0.0f};
            a = __builtin_amdgcn_mfma_f32_16x16x32_f16(a0, bfr[t][0], a, 0, 0, 0);
            a = __builtin_amdgcn_mfma_f32_16x16x32_f16(a1, bfr[t][1], a, 0, 0, 0);
            acc[t] = a;
        }

        // epilogue: one 8 B store per row r ({A,B,C,S} / {A,B,C,0})
        int jp  = (col & 7) >> 1;
        int sub = col & 1;
        #pragma unroll
        for (int r = 0; r < 4; r++) {
            int row = row0 + quad * 4 + r;
            if (row < N_NODES) {
                f16 last = (f16)0.0f;
                if (!pside) last = (f16)state[sbase + (size_t)row * H_ + jjglob];
                half4v pack = { (f16)acc[0][r], (f16)acc[1][r], (f16)acc[2][r], last };
                int boff = (row * rstride + jp) * 16 + sub * 8;
                *(half4v*)(dstBase + boff) = pack;
            }
        }
    }
    __syncthreads();   // barrier + vmcnt(0) drain: sU and Vscratch both ready

    // ---- Phase 2: packed-fp16 segment softmax (U from LDS, V from global)
    float sg = sigmoidf_(gate[0]);
    int jp   = tid & 3;      // jj pair within the eighth
    int slot = tid >> 2;     // 0..127

    const uint4*  ep4 = (const uint4*)edge_pack;   // 2 edges per uint4
    const float4* Vg  = (const float4*)vgBase;
    const char*   sUb = (const char*)sU;
    int jpo = jp << 4;

    int n = slot;
    uint4 E[8];
    #pragma unroll
    for (int k = 0; k < 8; k++) E[k] = ep4[n * 8 + k];

    #pragma unroll 1
    for (int it = 0; it < 4; it++) {
        // prefetch next n's edge records while we chew on this one
        int nn = n + 128;
        int nsafe = (nn < N_NODES) ? nn : n;
        uint4 En[8];
        #pragma unroll
        for (int k = 0; k < 8; k++) En[k] = ep4[nsafe * 8 + k];

        float4 vraw = Vg[n * 4 + jp];      // coalesced: wave reads 1 KB contig
        half2v vAB0 = *(half2v*)&vraw.x;   // {vA0, vB0}
        half2v vCS0 = *(half2v*)&vraw.y;   // {vC0, 0}
        half2v vAB1 = *(half2v*)&vraw.z;   // {vA1, vB1}
        half2v vCS1 = *(half2v*)&vraw.w;   // {vC1, 0}

        float l0 = 0.0f, num0 = 0.0f, l1 = 0.0f, num1 = 0.0f;
        #pragma unroll
        for (int e = 0; e < DEG; e++) {
            unsigned sxo = (e & 1) ? E[e >> 1].z : E[e >> 1].x;
            unsigned hx  = (e & 1) ? E[e >> 1].w : E[e >> 1].y;
            half2v hh = *(half2v*)&hx;
            float4 u = *(const float4*)(sUb + sxo + jpo);
            half2v uAB0 = *(half2v*)&u.x;   // {uA0, uB0}
            half2v uCS0 = *(half2v*)&u.y;   // {uC0, uS0}
            half2v uAB1 = *(half2v*)&u.z;
            half2v uCS1 = *(half2v*)&u.w;

            half2v ab0 = uAB0 + vAB0;       // v_pk_add_f16
            half2v ab1 = uAB1 + vAB1;
            half2v cs0 = uCS0 + vCS0;       // {C-term, S} (vS slot is 0)
            half2v cs1 = uCS1 + vCS1;

            float a0 = dot2f_(hh, ab0, (float)cs0.x);
            float a1 = dot2f_(hh, ab1, (float)cs1.x);
            a0 = fmaxf(a0, 0.01f * a0);     // leaky_relu (log2e pre-scaled)
            a1 = fmaxf(a1, 0.01f * a1);
            float p0 = EXP2F(a0);
            float p1 = EXP2F(a1);
            l0 += p0;  num0 = fmaf(p0, (float)cs0.y, num0);
            l1 += p1;  num1 = fmaf(p1, (float)cs1.y, num1);
        }
        float2 r;
        r.x = fmaxf(num0 / l0, 0.0f) * sg;
        r.y = fmaxf(num1 / l1, 0.0f) * sg;
        out2[((size_t)bt * N_NODES + n) * 32 + jh * 4 + jp] = r;

        n = nn;
        if (n >= N_NODES) break;
        #pragma unroll
        for (int k = 0; k < 8; k++) E[k] = En[k];
    }
}

// ---------------------------------------------------------------------------
// Workspace layout (bytes):
//   [0, 64000)           edge_pack (E uint2)
//   [131072, +49152)     wTh       (6*64*64 fp16, log2e-scaled)
//   [262144, +25165824)  Vscratch  (768 blocks x 32 KB)      total ~25.5 MB
// ---------------------------------------------------------------------------
extern "C" void kernel_launch(void* const* d_in, const int* in_sizes, int n_in,
                              void* d_out, int out_size, void* d_ws, size_t ws_size,
                              hipStream_t stream) {
    const float* state   = (const float*)d_in[0];
    const float* feature = (const float*)d_in[1];
    const float* dist    = (const float*)d_in[2];
    const float* W1      = (const float*)d_in[3];
    const float* b1      = (const float*)d_in[4];
    const float* W2      = (const float*)d_in[5];
    const float* b2      = (const float*)d_in[6];
    const float* W3      = (const float*)d_in[7];
    const float* b3      = (const float*)d_in[8];
    const float* gate    = (const float*)d_in[9];
    const int*   src     = (const int*)d_in[10];
    const int*   dst     = (const int*)d_in[11];
    float* out = (float*)d_out;
    (void)dst;

    char* ws = (char*)d_ws;
    uint2* edge_pack = (uint2*)(ws);
    f16*   wTh       = (f16*)(ws + 131072ULL);
    char*  Vscratch  = ws + 262144ULL;

    hipLaunchKernelGGL(prep_kernel, dim3(128), dim3(256), 0, stream,
                       feature, dist, W1, b1, W2, b2, src, W3, b3,
                       edge_pack, wTh);
    hipLaunchKernelGGL(fused_kernel, dim3(BT * 8), dim3(512), 0, stream,
                       state, wTh, edge_pack, gate, Vscratch, (float2*)out);
}

// Round 13
// 126.238 us; speedup vs baseline: 1.2685x; 1.2685x over previous
//
#include <hip/hip_runtime.h>
#include <hip/hip_fp16.h>
#include <math.h>

// Problem constants: N=500, DEG=16, E=8000, B=8, T=12 (BT=96), H=64, F=32
#define N_NODES 500
#define DEG     16
#define E_EDGES 8000
#define BT      96
#define H_      64
#define F_      32

typedef _Float16 f16;
typedef f16   half8v  __attribute__((ext_vector_type(8)));
typedef f16   half4v  __attribute__((ext_vector_type(4)));
typedef f16   half2v  __attribute__((ext_vector_type(2)));
typedef float f32x4v  __attribute__((ext_vector_type(4)));

#if __has_builtin(__builtin_amdgcn_exp2f)
#define EXP2F(x) __builtin_amdgcn_exp2f(x)
#else
#define EXP2F(x) exp2f(x)
#endif

#define LOG2E 1.44269504088896f

__device__ __forceinline__ float sigmoidf_(float x) {
    return 1.0f / (1.0f + __expf(-x));
}

__device__ __forceinline__ float dot2f_(half2v a, half2v b, float c) {
#if __has_builtin(__builtin_amdgcn_fdot2)
    return __builtin_amdgcn_fdot2(a, b, c, false);
#else
    return fmaf((float)a.x, (float)b.x, fmaf((float)a.y, (float)b.y, c));
#endif
}

// ---------------------------------------------------------------------------
// Kernel P (fused prep): blocks 0..31 = hyper MLP -> edge_pack
// {src*80 (LDS byte offset), h0h1 fp16x2}; blocks 32..127 = weight transpose
// -> wTh[c][jj][h] fp16, PRE-SCALED by log2(e) (leaky commutes with positive
// scale; fused kernel uses exp2 directly).
// plane c: 0=A_U 1=B_U 2=C_U 3=A_V 4=B_V 5=C_V; A=W3[0].view(128,64),
// B=W3[1], C=b3; U rows 0..63, V rows 64..127.
// ---------------------------------------------------------------------------
__global__ __launch_bounds__(256) void prep_kernel(
        const float* __restrict__ feature, const float* __restrict__ dist,
        const float* __restrict__ W1, const float* __restrict__ b1,
        const float* __restrict__ W2, const float* __restrict__ b2,
        const int* __restrict__ src,
        const float* __restrict__ W3, const float* __restrict__ b3,
        uint2* __restrict__ edge_pack, f16* __restrict__ wTh) {
    if (blockIdx.x >= 32) {
        int i = (blockIdx.x - 32) * 256 + threadIdx.x;
        if (i >= 6 * 64 * 64) return;
        int c  = i >> 12;
        int jj = (i >> 6) & 63;
        int h  = i & 63;
        const float* plane = (c % 3 == 0) ? W3 : (c % 3 == 1) ? (W3 + 8192) : b3;
        int rowbase = (c < 3) ? 0 : 64;
        wTh[i] = (f16)(plane[(rowbase + h) * 64 + jj] * LOG2E);
        return;
    }

    __shared__ float sW1[65 * 16];
    __shared__ float sb1[16];
    __shared__ float sW2[32];
    __shared__ float sb2[2];
    for (int i = threadIdx.x; i < 65 * 16; i += blockDim.x) sW1[i] = W1[i];
    if (threadIdx.x < 16) sb1[threadIdx.x] = b1[threadIdx.x];
    if (threadIdx.x < 32) sW2[threadIdx.x] = W2[threadIdx.x];
    if (threadIdx.x < 2)  sb2[threadIdx.x] = b2[threadIdx.x];
    __syncthreads();

    int e = blockIdx.x * 256 + threadIdx.x;
    if (e >= E_EDGES) return;
    int s = src[e];
    int d = e >> 4;                 // dst = repeat(arange(500),16)
    float fs[F_], fd[F_];
    const float4* f4 = (const float4*)feature;
    #pragma unroll
    for (int k = 0; k < 8; k++) {
        float4 v = f4[s * 8 + k];
        fs[4*k] = v.x; fs[4*k+1] = v.y; fs[4*k+2] = v.z; fs[4*k+3] = v.w;
    }
    #pragma unroll
    for (int k = 0; k < 8; k++) {
        float4 v = f4[d * 8 + k];
        fd[4*k] = v.x; fd[4*k+1] = v.y; fd[4*k+2] = v.z; fd[4*k+3] = v.w;
    }
    float dv = dist[e];

    float h1v[16];
    #pragma unroll
    for (int m = 0; m < 16; m++) {
        float acc = sb1[m] + dv * sW1[64 * 16 + m];
        #pragma unroll
        for (int f = 0; f < F_; f++) acc += fs[f] * sW1[f * 16 + m];
        #pragma unroll
        for (int f = 0; f < F_; f++) acc += fd[f] * sW1[(F_ + f) * 16 + m];
        h1v[m] = sigmoidf_(acc);
    }
    float o0 = sb2[0], o1 = sb2[1];
    #pragma unroll
    for (int m = 0; m < 16; m++) {
        o0 += h1v[m] * sW2[m * 2 + 0];
        o1 += h1v[m] * sW2[m * 2 + 1];
    }
    __half2 hh = __floats2half2_rn(sigmoidf_(o0), sigmoidf_(o1));
    uint2 ep;
    ep.x = (unsigned)(s * 80);      // pre-multiplied sU row byte-offset
    ep.y = *(unsigned*)&hh;
    edge_pack[e] = ep;
}

// ---------------------------------------------------------------------------
// Kernel F (fused GEMM + segment softmax). Grid = 8 jh x 96 bt, jh-major.
// 512 thr (8 waves). LDS = sU only (40 KB); V lives in per-block global
// scratch (zero reuse -> doesn't deserve LDS). __launch_bounds__(512, 6):
// VGPR cap ~80 -- R12's (512,8) capped at 64 -> E[]/bfr[] SPILLED TO
// SCRATCH (VGPR_Count=32, WRITE_SIZE 135 MB, 70+ us). To fit under 80,
// phase 2's En[] prefetch double-buffer is REMOVED (-32 VGPRs); latency
// hiding now comes from occupancy: 40.4 KB LDS and <=80 VGPR both allow
// 3 blocks/CU = 24 waves/CU (R11: 16).
// ---------------------------------------------------------------------------
__global__ __launch_bounds__(512, 6) void fused_kernel(
        const float* __restrict__ state,
        const f16* __restrict__ wTh,
        const uint2* __restrict__ edge_pack,
        const float* __restrict__ gate,
        char* __restrict__ Vscratch,          // 32 KB per block
        float2* __restrict__ out2) {
    __shared__ float4 sU[N_NODES * 5];   // 40 KB, 80 B per node row

    int bt  = blockIdx.x % BT;
    int jh  = blockIdx.x / BT;
    int tid = threadIdx.x;
    int wv   = tid >> 6;
    int lane = tid & 63;
    int col  = lane & 15;
    int quad = lane >> 4;

    char* vgBase = Vscratch + (size_t)blockIdx.x * 32768;

    // B fragments: tile t covers plane t + 3*(col>>3), jj = jh*8 + (col&7)
    int jjglob = jh * 8 + (col & 7);
    int pside  = col >> 3;              // 0 = U planes, 1 = V planes
    half8v bfr[3][2];
    #pragma unroll
    for (int t = 0; t < 3; t++) {
        int plane = t + 3 * pside;
        const f16* wp = wTh + (plane * 64 + jjglob) * 64;
        bfr[t][0] = *(const half8v*)&wp[quad * 8];
        bfr[t][1] = *(const half8v*)&wp[32 + quad * 8];
    }

    const size_t sbase = (size_t)bt * N_NODES * H_;
    char* dstBase = pside ? vgBase : (char*)sU;
    int   rstride = pside ? 4 : 5;      // float4 row stride

    // ---- Phase 1: GEMM; U -> LDS pack, V -> global scratch
    for (int pass = 0; pass < 4; pass++) {
        int row0 = pass * 128 + wv * 16;
        int arow = row0 + col;
        int arowc = arow < N_NODES ? arow : N_NODES - 1;   // clamp tail reads
        const float* srow = state + sbase + (size_t)arowc * H_;
        float4 p0 = *(const float4*)&srow[quad * 8];
        float4 p1 = *(const float4*)&srow[quad * 8 + 4];
        float4 p2 = *(const float4*)&srow[32 + quad * 8];
        float4 p3 = *(const float4*)&srow[32 + quad * 8 + 4];
        half8v a0 = { (f16)p0.x,(f16)p0.y,(f16)p0.z,(f16)p0.w,
                      (f16)p1.x,(f16)p1.y,(f16)p1.z,(f16)p1.w };
        half8v a1 = { (f16)p2.x,(f16)p2.y,(f16)p2.z,(f16)p2.w,
                      (f16)p3.x,(f16)p3.y,(f16)p3.z,(f16)p3.w };

        f32x4v acc[3];
        #pragma unroll
        for (int t = 0; t < 3; t++) {
            f32x4v a = {0.0f, 0.0f, 0.0f, 0.0f};
            a = __builtin_amdgcn_mfma_f32_16x16x32_f16(a0, bfr[t][0], a, 0, 0, 0);
            a = __builtin_amdgcn_mfma_f32_16x16x32_f16(a1, bfr[t][1], a, 0, 0, 0);
            acc[t] = a;
        }

        // epilogue: one 8 B store per row r ({A,B,C,S} / {A,B,C,0})
        int jp  = (col & 7) >> 1;
        int sub = col & 1;
        #pragma unroll
        for (int r = 0; r < 4; r++) {
            int row = row0 + quad * 4 + r;
            if (row < N_NODES) {
                f16 last = (f16)0.0f;
                if (!pside) last = (f16)state[sbase + (size_t)row * H_ + jjglob];
                half4v pack = { (f16)acc[0][r], (f16)acc[1][r], (f16)acc[2][r], last };
                int boff = (row * rstride + jp) * 16 + sub * 8;
                *(half4v*)(dstBase + boff) = pack;
            }
        }
    }
    __syncthreads();   // barrier + vmcnt(0) drain: sU and Vscratch both ready

    // ---- Phase 2: packed-fp16 segment softmax (U from LDS, V from global)
    float sg = sigmoidf_(gate[0]);
    int jp   = tid & 3;      // jj pair within the eighth
    int slot = tid >> 2;     // 0..127

    const uint4*  ep4 = (const uint4*)edge_pack;   // 2 edges per uint4
    const float4* Vg  = (const float4*)vgBase;
    const char*   sUb = (const char*)sU;
    int jpo = jp << 4;

    #pragma unroll 1
    for (int n = slot; n < N_NODES; n += 128) {
        uint4 E[8];
        #pragma unroll
        for (int k = 0; k < 8; k++) E[k] = ep4[n * 8 + k];

        float4 vraw = Vg[n * 4 + jp];      // coalesced: wave reads 1 KB contig
        half2v vAB0 = *(half2v*)&vraw.x;   // {vA0, vB0}
        half2v vCS0 = *(half2v*)&vraw.y;   // {vC0, 0}
        half2v vAB1 = *(half2v*)&vraw.z;   // {vA1, vB1}
        half2v vCS1 = *(half2v*)&vraw.w;   // {vC1, 0}

        float l0 = 0.0f, num0 = 0.0f, l1 = 0.0f, num1 = 0.0f;
        #pragma unroll
        for (int e = 0; e < DEG; e++) {
            unsigned sxo = (e & 1) ? E[e >> 1].z : E[e >> 1].x;
            unsigned hx  = (e & 1) ? E[e >> 1].w : E[e >> 1].y;
            half2v hh = *(half2v*)&hx;
            float4 u = *(const float4*)(sUb + sxo + jpo);
            half2v uAB0 = *(half2v*)&u.x;   // {uA0, uB0}
            half2v uCS0 = *(half2v*)&u.y;   // {uC0, uS0}
            half2v uAB1 = *(half2v*)&u.z;
            half2v uCS1 = *(half2v*)&u.w;

            half2v ab0 = uAB0 + vAB0;       // v_pk_add_f16
            half2v ab1 = uAB1 + vAB1;
            half2v cs0 = uCS0 + vCS0;       // {C-term, S} (vS slot is 0)
            half2v cs1 = uCS1 + vCS1;

            float a0 = dot2f_(hh, ab0, (float)cs0.x);
            float a1 = dot2f_(hh, ab1, (float)cs1.x);
            a0 = fmaxf(a0, 0.01f * a0);     // leaky_relu (log2e pre-scaled)
            a1 = fmaxf(a1, 0.01f * a1);
            float p0 = EXP2F(a0);
            float p1 = EXP2F(a1);
            l0 += p0;  num0 = fmaf(p0, (float)cs0.y, num0);
            l1 += p1;  num1 = fmaf(p1, (float)cs1.y, num1);
        }
        float2 r;
        r.x = fmaxf(num0 / l0, 0.0f) * sg;
        r.y = fmaxf(num1 / l1, 0.0f) * sg;
        out2[((size_t)bt * N_NODES + n) * 32 + jh * 4 + jp] = r;
    }
}

// ---------------------------------------------------------------------------
// Workspace layout (bytes):
//   [0, 64000)           edge_pack (E uint2)
//   [131072, +49152)     wTh       (6*64*64 fp16, log2e-scaled)
//   [262144, +25165824)  Vscratch  (768 blocks x 32 KB)      total ~25.5 MB
// ---------------------------------------------------------------------------
extern "C" void kernel_launch(void* const* d_in, const int* in_sizes, int n_in,
                              void* d_out, int out_size, void* d_ws, size_t ws_size,
                              hipStream_t stream) {
    const float* state   = (const float*)d_in[0];
    const float* feature = (const float*)d_in[1];
    const float* dist    = (const float*)d_in[2];
    const float* W1      = (const float*)d_in[3];
    const float* b1      = (const float*)d_in[4];
    const float* W2      = (const float*)d_in[5];
    const float* b2      = (const float*)d_in[6];
    const float* W3      = (const float*)d_in[7];
    const float* b3      = (const float*)d_in[8];
    const float* gate    = (const float*)d_in[9];
    const int*   src     = (const int*)d_in[10];
    const int*   dst     = (const int*)d_in[11];
    float* out = (float*)d_out;
    (void)dst;

    char* ws = (char*)d_ws;
    uint2* edge_pack = (uint2*)(ws);
    f16*   wTh       = (f16*)(ws + 131072ULL);
    char*  Vscratch  = ws + 262144ULL;

    hipLaunchKernelGGL(prep_kernel, dim3(128), dim3(256), 0, stream,
                       feature, dist, W1, b1, W2, b2, src, W3, b3,
                       edge_pack, wTh);
    hipLaunchKernelGGL(fused_kernel, dim3(BT * 8), dim3(512), 0, stream,
                       state, wTh, edge_pack, gate, Vscratch, (float2*)out);
}